// Round 10
// baseline (363.472 us; speedup 1.0000x reference)
//
#include <hip/hip_runtime.h>
#include <hip/hip_bf16.h>
#include <math.h>

#define BB 16
#define TT 64
#define HWXY 512
#define EE 256
#define VV 128

typedef __bf16 bf16x8 __attribute__((ext_vector_type(8)));
typedef unsigned short u16x8 __attribute__((ext_vector_type(8)));
typedef float f32x4 __attribute__((ext_vector_type(4)));
typedef unsigned short u16;

__device__ __forceinline__ f32x4 mfma16(bf16x8 a, bf16x8 b, f32x4 c) {
    return __builtin_amdgcn_mfma_f32_16x16x32_bf16(a, b, c, 0, 0, 0);
}

__device__ __forceinline__ unsigned short f2bf(float f) {
    union { float f; unsigned int i; } v; v.f = f;
    unsigned int x = v.i;
    return (unsigned short)((x + 0x7fffu + ((x >> 16) & 1u)) >> 16);  // RNE
}

__device__ __forceinline__ float bf2f(unsigned short u) {
    union { unsigned int i; float f; } v; v.i = ((unsigned int)u) << 16;
    return v.f;
}

__device__ __forceinline__ u16x8 pack8(float4 v0, float4 v1) {
    u16x8 o;
    o[0] = f2bf(v0.x); o[1] = f2bf(v0.y); o[2] = f2bf(v0.z); o[3] = f2bf(v0.w);
    o[4] = f2bf(v1.x); o[5] = f2bf(v1.y); o[6] = f2bf(v1.z); o[7] = f2bf(v1.w);
    return o;
}

__device__ __forceinline__ void dma16(const void* g, void* l) {
    __builtin_amdgcn_global_load_lds(
        (const __attribute__((address_space(1))) void*)g,
        (__attribute__((address_space(3))) void*)l, 16, 0, 0);
}

#define VMWAIT0() do { asm volatile("s_waitcnt vmcnt(0)" ::: "memory"); \
                       __builtin_amdgcn_sched_barrier(0); } while (0)

// Per-batch barrier among the 16 blocks of batch b (same XCD by mapping).
__device__ __forceinline__ void bar_wait(unsigned int* c) {
    __threadfence();
    __syncthreads();
    if (threadIdx.x == 0) {
        __hip_atomic_fetch_add(c, 1u, __ATOMIC_RELEASE, __HIP_MEMORY_SCOPE_AGENT);
        while (__hip_atomic_load(c, __ATOMIC_ACQUIRE, __HIP_MEMORY_SCOPE_AGENT) < 16u) {}
    }
    __syncthreads();
    __threadfence();
    __builtin_amdgcn_sched_barrier(0);
}
__device__ __forceinline__ void bar_arrive(unsigned int* c) {
    __threadfence();
    __syncthreads();
    if (threadIdx.x == 0)
        __hip_atomic_fetch_add(c, 1u, __ATOMIC_RELEASE, __HIP_MEMORY_SCOPE_AGENT);
}

// ---------------------------------------------------------------------------
// Setup (unchanged, runs once)
// ---------------------------------------------------------------------------
__global__ __launch_bounds__(256) void k_setup(
    const float* __restrict__ enc, const float* __restrict__ dec,
    const int* __restrict__ labels, const float* __restrict__ embed,
    const float* __restrict__ conv_w, const float* __restrict__ W_w,
    const float* __restrict__ Wo_w,
    u16* __restrict__ s_bf, u16* __restrict__ a_bf,
    u16* __restrict__ dec_bf, u16* __restrict__ resT,
    u16* __restrict__ convwT, u16* __restrict__ WT, u16* __restrict__ Wo_bf) {
    __shared__ unsigned short tl[64][66];
    int bid = blockIdx.x;
    if (bid < 512) {
        const int b = bid >> 5, rem = bid & 31;
        const int s0 = (rem >> 2) << 6, e0 = (rem & 3) << 6;
#pragma unroll
        for (int it = 0; it < 16; ++it) {
            int lin = threadIdx.x + it * 256;
            int sl = lin >> 6, el = lin & 63;
            int src = (b * HWXY + s0 + sl) * EE + e0 + el;
            float dv = dec[src];
            dec_bf[src] = f2bf(dv);
            tl[sl][el] = f2bf(enc[src] + dv);
        }
        __syncthreads();
#pragma unroll
        for (int it = 0; it < 16; ++it) {
            int lin = threadIdx.x + it * 256;
            int el = lin >> 6, sl = lin & 63;
            resT[(b * EE + e0 + el) * HWXY + s0 + sl] = tl[sl][el];
        }
        return;
    }
    bid -= 512;
    if (bid < 96) {
        const int c0 = (bid >> 3) << 6, j0 = (bid & 7) << 6;
#pragma unroll
        for (int it = 0; it < 16; ++it) {
            int lin = threadIdx.x + it * 256;
            int cl = lin >> 6, jl = lin & 63;
            tl[cl][jl] = f2bf(conv_w[(c0 + cl) * 512 + j0 + jl]);
        }
        __syncthreads();
#pragma unroll
        for (int it = 0; it < 16; ++it) {
            int lin = threadIdx.x + it * 256;
            int jl = lin >> 6, cl = lin & 63;
            convwT[(j0 + jl) * 768 + c0 + cl] = tl[cl][jl];
        }
        return;
    }
    bid -= 96;
    if (bid < 16) {
        const int c0 = (bid >> 2) << 6, j0 = (bid & 3) << 6;
#pragma unroll
        for (int it = 0; it < 16; ++it) {
            int lin = threadIdx.x + it * 256;
            int cl = lin >> 6, jl = lin & 63;
            tl[cl][jl] = f2bf(W_w[(c0 + cl) * 256 + j0 + jl]);
        }
        __syncthreads();
#pragma unroll
        for (int it = 0; it < 16; ++it) {
            int lin = threadIdx.x + it * 256;
            int el = lin >> 6, pl = lin & 63;
            WT[(j0 + el) * 256 + c0 + pl] = tl[pl][el];
        }
        return;
    }
    bid -= 16;
    int i8 = (bid * 256 + threadIdx.x) * 8;
    const int n1 = BB * TT * EE;
    if (i8 < n1) {
        int b = i8 >> 14, t = (i8 >> 8) & 63, e = i8 & 255;
        int lab = labels[b * TT + t];
        const float* ep = embed + lab * EE + e;
        float4 v0 = *(const float4*)ep, v1 = *(const float4*)(ep + 4);
        u16x8 p = pack8(v0, v1);
        *(u16x8*)(s_bf + i8) = p;
        *(u16x8*)(a_bf + i8) = p;
        return;
    }
    i8 -= n1;
    float4 v0 = *(const float4*)(Wo_w + i8), v1 = *(const float4*)(Wo_w + i8 + 4);
    *(u16x8*)(Wo_bf + i8) = pack8(v0, v1);
}

// ---------------------------------------------------------------------------
// k_precomp (runs once): G = dec @ W, base = (s + W_b) . dec^T
// ---------------------------------------------------------------------------
__global__ __launch_bounds__(256) void k_precomp(
    const u16* __restrict__ dec_bf, const u16* __restrict__ WT,
    const u16* __restrict__ s_bf, const float* __restrict__ W_b,
    u16* __restrict__ G, float* __restrict__ base_g) {
    __shared__ __align__(16) char smem[98304];
    char* const As = smem;
    char* const Bs = smem + 32768;
    const int tid = threadIdx.x;
    const int w = tid >> 6, L = tid & 63, l16 = L & 15, lg = L >> 4;
    int bid = blockIdx.x;

    if (bid < 256) {
        const int b = bid >> 4, st = (bid >> 1) & 7, et = bid & 1;
#pragma unroll
        for (int i = 0; i < 8; ++i) {
            const int p = w * 8 + i;
            const int r = 2 * p + (L >> 5);
            dma16(dec_bf + (b * HWXY + st * 64 + r) * EE + (((L & 31) ^ (r & 7)) << 3),
                  As + p * 1024);
        }
#pragma unroll
        for (int i = 0; i < 16; ++i) {
            const int slot = w * 16 + i;
            const int kc = slot >> 3, nf = slot & 7;
            dma16(WT + (et * 128 + nf * 16 + l16) * EE + kc * 32 + lg * 8,
                  Bs + slot * 1024);
        }
        VMWAIT0();
        __syncthreads();
        f32x4 acc[4][2] = {{{0,0,0,0},{0,0,0,0}},{{0,0,0,0},{0,0,0,0}},
                           {{0,0,0,0},{0,0,0,0}},{{0,0,0,0},{0,0,0,0}}};
#pragma unroll
        for (int kc = 0; kc < 8; ++kc) {
#pragma unroll
            for (int m = 0; m < 4; ++m) {
                const int arow = m * 16 + l16;
                const bf16x8 af = *(const bf16x8*)(
                    As + arow * 512 + (((kc * 4 + lg) ^ (arow & 7)) << 4));
                acc[m][0] = mfma16(af, *(const bf16x8*)(Bs + (kc * 8 + w * 2) * 1024 + L * 16), acc[m][0]);
                acc[m][1] = mfma16(af, *(const bf16x8*)(Bs + (kc * 8 + w * 2 + 1) * 1024 + L * 16), acc[m][1]);
            }
        }
#pragma unroll
        for (int m = 0; m < 4; ++m)
#pragma unroll
            for (int nf = 0; nf < 2; ++nf)
#pragma unroll
                for (int j = 0; j < 4; ++j) {
                    const int s = st * 64 + m * 16 + lg * 4 + j;
                    const int e = et * 128 + w * 32 + nf * 16 + l16;
                    G[(b * HWXY + s) * EE + e] = f2bf(acc[m][nf][j]);
                }
    } else {
        bid -= 256;
        const int b = bid >> 3, st = bid & 7;
#pragma unroll
        for (int it = 0; it < 8; ++it) {
            int unit = tid + it * 256;
            int row = unit >> 5, ch = unit & 31;
            u16x8 v = *(const u16x8*)(s_bf + (b * TT + row) * EE + ch * 8);
            u16x8 o;
#pragma unroll
            for (int k = 0; k < 8; ++k) o[k] = f2bf(bf2f(v[k]) + W_b[ch * 8 + k]);
            *(u16x8*)(As + row * 512 + ((ch ^ (row & 7)) << 4)) = o;
        }
#pragma unroll
        for (int i = 0; i < 8; ++i) {
            const int slot = w * 8 + i;
            const int kc = slot >> 2, nf = slot & 3;
            dma16(dec_bf + (b * HWXY + st * 64 + nf * 16 + l16) * EE + kc * 32 + lg * 8,
                  Bs + slot * 1024);
        }
        VMWAIT0();
        __syncthreads();
        f32x4 acc[4] = {{0,0,0,0},{0,0,0,0},{0,0,0,0},{0,0,0,0}};
        const int arow = w * 16 + l16;
#pragma unroll
        for (int kc = 0; kc < 8; ++kc) {
            const bf16x8 af = *(const bf16x8*)(
                As + arow * 512 + (((kc * 4 + lg) ^ (arow & 7)) << 4));
#pragma unroll
            for (int nf = 0; nf < 4; ++nf)
                acc[nf] = mfma16(af, *(const bf16x8*)(Bs + (kc * 4 + nf) * 1024 + L * 16), acc[nf]);
        }
#pragma unroll
        for (int nf = 0; nf < 4; ++nf)
#pragma unroll
            for (int j = 0; j < 4; ++j) {
                const int t = w * 16 + lg * 4 + j;
                base_g[(b * TT + t) * HWXY + st * 64 + nf * 16 + l16] = acc[nf][j];
            }
    }
}

// ---------------------------------------------------------------------------
// Fused layer: conv+GLU -> [bar] -> scores+psoftmax -> [bar] -> attn (+logits).
// grid 256, block 256. id = u*16 + (b>>3)*8 + (b&7)  =>  id%8 == b%8 (XCD-local).
// Per-batch barriers among the 16 units of b via device-scope atomics.
// ---------------------------------------------------------------------------
template <int LAST>
__global__ __launch_bounds__(256) void k_layer_fused(
    const u16* __restrict__ a_in, u16* __restrict__ a_out,
    const u16* __restrict__ convwT, const float* __restrict__ conv_b,
    u16* __restrict__ z_bf, const u16* __restrict__ G,
    const float* __restrict__ base_g, u16* __restrict__ p_bf,
    float* __restrict__ m_part, float* __restrict__ s_part,
    const u16* __restrict__ resT, const u16* __restrict__ Wo_bf,
    const float* __restrict__ Wo_b, float* __restrict__ out,
    unsigned int* __restrict__ ctr) {
    __shared__ __align__(16) char smem[74240];
    const int id = blockIdx.x;
    const int u = id >> 4;
    const int b = (((id >> 3) & 1) << 3) | (id & 7);
    const int tid = threadIdx.x;
    const int w = tid >> 6, L = tid & 63, l16 = L & 15, lg = L >> 4;
    unsigned int* cb = ctr + b * 4;

    // ================= Phase 1: CONV (ct = u) =================
    {
        char* const As = smem;            // 66 x 512 swizzled
        char* const Bs = smem + 33792;    // 24 slots x 1KB (chunked)
        // A halo: rows 1..64 via DMA, rows 0 & 65 zeroed
#pragma unroll
        for (int i = 0; i < 8; ++i) {
            const int p = w * 8 + i;
            const int r = 1 + 2 * p + (L >> 5);
            dma16(a_in + (b * TT + r - 1) * EE + (((L & 31) ^ (r & 7)) << 3),
                  As + 512 + p * 1024);
        }
        if (tid < 64) {
            char* dst = (tid < 32) ? (As + tid * 16) : (As + 65 * 512 + (tid - 32) * 16);
            *(u16x8*)dst = (u16x8){0,0,0,0,0,0,0,0};
        }
        f32x4 za = {0,0,0,0}, zb = {0,0,0,0};
#pragma unroll
        for (int c = 0; c < 2; ++c) {
#pragma unroll
            for (int i = 0; i < 6; ++i) {
                const int slot = w * 6 + i;             // 0..23
                const int kcg = c * 12 + (slot >> 1), half = slot & 1;
                dma16(convwT + (u * 16 + l16 + half * 256) * 768 + kcg * 32 + lg * 8,
                      Bs + slot * 1024);
            }
            VMWAIT0();
            __syncthreads();
#pragma unroll
            for (int kcl = 0; kcl < 12; ++kcl) {
                const int kcg = c * 12 + kcl;
                const int kt = kcg >> 3, ec = kcg & 7;
                const int arow = w * 16 + l16 + kt;
                const bf16x8 af = *(const bf16x8*)(
                    As + arow * 512 + ((ec * 64 + lg * 16) ^ ((arow & 7) << 4)));
                za = mfma16(af, *(const bf16x8*)(Bs + (kcl * 2) * 1024 + L * 16), za);
                zb = mfma16(af, *(const bf16x8*)(Bs + (kcl * 2 + 1) * 1024 + L * 16), zb);
            }
            if (c == 0) __syncthreads();   // protect Bs reuse
        }
        const int p = u * 16 + l16;
        const float cbA = conv_b[p], cbB = conv_b[p + 256];
#pragma unroll
        for (int j = 0; j < 4; ++j) {
            const int t = w * 16 + lg * 4 + j;
            const float v = za[j] + cbA, q = zb[j] + cbB;
            z_bf[(b * TT + t) * EE + p] = f2bf(v / (1.0f + __expf(-q)));
        }
    }
    bar_wait(cb + 0);

    // ================= Phase 2: SCORES (st = u) =================
    {
        char* const Zs = smem;                 // 32 KB
        char* const Gs = smem + 32768;         // 16 KB
        float* const basel = (float*)(smem + 49152);   // 64 x 36
        const int st = u;
#pragma unroll
        for (int i = 0; i < 8; ++i) {
            const int p = w * 8 + i;
            const int r = 2 * p + (L >> 5);
            dma16(z_bf + (b * TT + r) * EE + (((L & 31) ^ (r & 7)) << 3), Zs + p * 1024);
        }
#pragma unroll
        for (int i = 0; i < 4; ++i) {
            const int slot = w * 4 + i;
            const int kc = slot >> 1, nf = slot & 1;
            dma16(G + (b * HWXY + st * 32 + nf * 16 + l16) * EE + kc * 32 + lg * 8,
                  Gs + slot * 1024);
        }
        {
            const int row = tid >> 2, c0 = (tid & 3) * 8;
            const float* src = base_g + (b * TT + row) * HWXY + st * 32 + c0;
            float4 v0 = *(const float4*)src, v1 = *(const float4*)(src + 4);
            *(float4*)(basel + row * 36 + c0) = v0;
            *(float4*)(basel + row * 36 + c0 + 4) = v1;
        }
        VMWAIT0();
        __syncthreads();

        f32x4 sc[2] = {{0,0,0,0},{0,0,0,0}};
        const int arow = w * 16 + l16;
#pragma unroll
        for (int kc = 0; kc < 8; ++kc) {
            const bf16x8 af = *(const bf16x8*)(
                Zs + arow * 512 + (((kc * 4 + lg) ^ (arow & 7)) << 4));
            sc[0] = mfma16(af, *(const bf16x8*)(Gs + (kc * 2) * 1024 + L * 16), sc[0]);
            sc[1] = mfma16(af, *(const bf16x8*)(Gs + (kc * 2 + 1) * 1024 + L * 16), sc[1]);
        }
        float pm[4], ps[4];
#pragma unroll
        for (int j = 0; j < 4; ++j) {
            const int row = w * 16 + lg * 4 + j;
            sc[0][j] += basel[row * 36 + l16];
            sc[1][j] += basel[row * 36 + 16 + l16];
            float m = fmaxf(sc[0][j], sc[1][j]);
#pragma unroll
            for (int off = 8; off >= 1; off >>= 1) m = fmaxf(m, __shfl_xor(m, off));
            pm[j] = m;
            const float p0 = __expf(sc[0][j] - m);
            const float p1 = __expf(sc[1][j] - m);
            sc[0][j] = p0; sc[1][j] = p1;
            float s = p0 + p1;
#pragma unroll
            for (int off = 8; off >= 1; off >>= 1) s += __shfl_xor(s, off);
            ps[j] = s;
        }
        if (l16 == 0) {
#pragma unroll
            for (int j = 0; j < 4; ++j) {
                const int t = w * 16 + lg * 4 + j;
                m_part[(b * 16 + st) * TT + t] = pm[j];
                s_part[(b * 16 + st) * TT + t] = ps[j];
            }
        }
#pragma unroll
        for (int nf = 0; nf < 2; ++nf)
#pragma unroll
            for (int j = 0; j < 4; ++j) {
                const int t = w * 16 + lg * 4 + j;
                p_bf[(b * TT + t) * HWXY + st * 32 + nf * 16 + l16] = f2bf(sc[nf][j]);
            }
    }
    bar_wait(cb + 1);

    // ================= Phase 3: ATTN (et = u>>1, tt = u&1) =================
    {
        char* const Ps = smem;                 // 32 KB
        char* const Bs = smem + 32768;         // 32 KB
        u16* const Zr = (u16*)(smem + 65536);  // 2 KB
        float* const mp = (float*)(smem + 67584);
        float* const sp = (float*)(smem + 69632);
        const int et = u >> 1, tt = u & 1;
#pragma unroll
        for (int i = 0; i < 8; ++i) {
            const int r = w * 8 + i;
            dma16(p_bf + (b * TT + tt * 32 + r) * HWXY + ((L ^ (r & 7)) << 3), Ps + r * 1024);
        }
#pragma unroll
        for (int i = 0; i < 8; ++i) {
            const int slot = w * 8 + i;
            const int kc = slot >> 1, nf = slot & 1;
            dma16(resT + (b * EE + et * 32 + nf * 16 + l16) * HWXY + kc * 32 + lg * 8,
                  Bs + slot * 1024);
        }
        {
            if (tid < 128) {
                const int t = tid >> 2, part = tid & 3;
                *(u16x8*)(Zr + t * 32 + part * 8) =
                    *(const u16x8*)(z_bf + (b * TT + tt * 32 + t) * EE + et * 32 + part * 8);
            }
            const int stl = tid >> 5, tl = tid & 31;
            mp[tid] = m_part[(b * 16 + stl) * TT + tt * 32 + tl];
            sp[tid] = s_part[(b * 16 + stl) * TT + tt * 32 + tl];
            mp[tid + 256] = m_part[(b * 16 + stl + 8) * TT + tt * 32 + tl];
            sp[tid + 256] = s_part[(b * 16 + stl + 8) * TT + tt * 32 + tl];
        }
        VMWAIT0();
        __syncthreads();

        const int mg = w >> 1, nh = w & 1;
        float corr[4][16];
#pragma unroll
        for (int j = 0; j < 4; ++j) {
            const int row = mg * 16 + lg * 4 + j;
            float mgl = mp[row];
#pragma unroll
            for (int s = 1; s < 16; ++s) mgl = fmaxf(mgl, mp[s * 32 + row]);
            float S = 0.f;
#pragma unroll
            for (int s = 0; s < 16; ++s) {
                const float c = __expf(mp[s * 32 + row] - mgl);
                corr[j][s] = c;
                S += sp[s * 32 + row] * c;
            }
            const float is = 1.0f / S;
#pragma unroll
            for (int s = 0; s < 16; ++s) corr[j][s] *= is;
        }
        f32x4 ca = {0,0,0,0};
        const int arow = mg * 16 + l16;
#pragma unroll
        for (int st = 0; st < 16; ++st) {
            const bf16x8 af = *(const bf16x8*)(
                Ps + arow * 1024 + (((st * 4 + lg) ^ (arow & 7)) << 4));
            f32x4 t0 = mfma16(af, *(const bf16x8*)(Bs + (st * 2 + nh) * 1024 + L * 16),
                              (f32x4){0,0,0,0});
#pragma unroll
            for (int j = 0; j < 4; ++j) ca[j] += t0[j] * corr[j][st];
        }
#pragma unroll
        for (int j = 0; j < 4; ++j) {
            const int row = mg * 16 + lg * 4 + j;
            a_out[(b * TT + tt * 32 + row) * EE + et * 32 + nh * 16 + l16] =
                f2bf(ca[j] + bf2f(Zr[row * 32 + nh * 16 + l16]));
        }
    }
    if (!LAST) return;

    // ================= Phase 4 (LAST): LOGITS (units 0..3, tt = u) =========
    if (u >= 4) { bar_arrive(cb + 2); return; }
    bar_wait(cb + 2);
    {
        char* const Aa = smem;                 // 8 KB
        char* const Ws = smem + 8192;          // 64 KB
        float* const red_m = (float*)(smem + 73728);
        float* const red_s = (float*)(smem + 73984);
        const int tt = u;
#pragma unroll
        for (int i = 0; i < 2; ++i) {
            const int p = w * 2 + i;
            const int row = p * 2 + (L >> 5);
            dma16(a_out + (b * TT + tt * 16 + row) * EE + (((L & 31) ^ (row & 7)) << 3),
                  Aa + p * 1024);
        }
#pragma unroll
        for (int i = 0; i < 16; ++i) {
            const int slot = w * 16 + i;
            const int kc = slot >> 3, vg = slot & 7;
            dma16(Wo_bf + (vg * 16 + l16) * EE + kc * 32 + lg * 8, Ws + slot * 1024);
        }
        VMWAIT0();
        __syncthreads();

        f32x4 l0 = {0,0,0,0}, l1 = {0,0,0,0};
#pragma unroll
        for (int kc = 0; kc < 8; ++kc) {
            const bf16x8 af = *(const bf16x8*)(
                Aa + l16 * 512 + ((kc * 64 + lg * 16) ^ ((l16 & 7) << 4)));
            l0 = mfma16(af, *(const bf16x8*)(Ws + (kc * 8 + w * 2) * 1024 + L * 16), l0);
            l1 = mfma16(af, *(const bf16x8*)(Ws + (kc * 8 + w * 2 + 1) * 1024 + L * 16), l1);
        }
        const int v0 = w * 32 + l16, v1 = v0 + 16;
        const float wb0 = Wo_b[v0], wb1 = Wo_b[v1];
        float lv0[4], lv1[4], mg[4];
#pragma unroll
        for (int j = 0; j < 4; ++j) {
            lv0[j] = l0[j] + wb0;
            lv1[j] = l1[j] + wb1;
            float m = fmaxf(lv0[j], lv1[j]);
#pragma unroll
            for (int off = 8; off >= 1; off >>= 1) m = fmaxf(m, __shfl_xor(m, off));
            if (l16 == 0) red_m[(lg * 4 + j) * 4 + w] = m;
        }
        __syncthreads();
#pragma unroll
        for (int j = 0; j < 4; ++j) {
            const int row = lg * 4 + j;
            float m = red_m[row * 4 + 0];
#pragma unroll
            for (int ww = 1; ww < 4; ++ww) m = fmaxf(m, red_m[row * 4 + ww]);
            mg[j] = m;
            float s = __expf(lv0[j] - m) + __expf(lv1[j] - m);
#pragma unroll
            for (int off = 8; off >= 1; off >>= 1) s += __shfl_xor(s, off);
            if (l16 == 0) red_s[row * 4 + w] = s;
        }
        __syncthreads();
#pragma unroll
        for (int j = 0; j < 4; ++j) {
            const int row = lg * 4 + j;
            float s = red_s[row * 4 + 0] + red_s[row * 4 + 1] + red_s[row * 4 + 2] + red_s[row * 4 + 3];
            const float lse = mg[j] + __logf(s);
            const int gt = b * TT + tt * 16 + row;
            out[gt * VV + v0] = lv0[j] - lse;
            out[gt * VV + v1] = lv1[j] - lse;
        }
    }
}

// ---------------------------------------------------------------------------
extern "C" void kernel_launch(void* const* d_in, const int* in_sizes, int n_in,
                              void* d_out, int out_size, void* d_ws, size_t ws_size,
                              hipStream_t stream) {
    const float* enc    = (const float*)d_in[0];
    const float* dec    = (const float*)d_in[1];
    const int*   labels = (const int*)d_in[2];
    const float* embed  = (const float*)d_in[3];
    const float* conv_w = (const float*)d_in[4];
    const float* conv_b = (const float*)d_in[5];
    const float* W_w    = (const float*)d_in[6];
    const float* W_b    = (const float*)d_in[7];
    const float* Wo_w   = (const float*)d_in[8];
    const float* Wo_b   = (const float*)d_in[9];
    float* out = (float*)d_out;
    char* ws = (char*)d_ws;

    u16*   a0     = (u16*)(ws + 0x000000);
    u16*   a1     = (u16*)(ws + 0x080000);
    u16*   s_bf   = (u16*)(ws + 0x100000);
    u16*   dec_bf = (u16*)(ws + 0x180000);
    u16*   resT   = (u16*)(ws + 0x580000);
    u16*   convwT = (u16*)(ws + 0x980000);
    u16*   WT     = (u16*)(ws + 0xA40000);
    u16*   Wo_bf  = (u16*)(ws + 0xA60000);
    u16*   z_bf   = (u16*)(ws + 0xA80000);
    u16*   p_bf   = (u16*)(ws + 0xB00000);
    float* m_part = (float*)(ws + 0xC00000);
    float* s_part = (float*)(ws + 0xC10000);
    float* base_g = (float*)(ws + 0xC20000);
    u16*   G      = (u16*)(ws + 0xE20000);
    unsigned int* ctr = (unsigned int*)(ws + 0x1220000);   // 3 x 64 uints

    hipMemsetAsync(ctr, 0, 3 * 64 * sizeof(unsigned int), stream);

    k_setup<<<768, 256, 0, stream>>>(enc, dec, labels, embed, conv_w, W_w, Wo_w,
                                     s_bf, a0, dec_bf, resT, convwT, WT, Wo_bf);
    k_precomp<<<384, 256, 0, stream>>>(dec_bf, WT, s_bf, W_b, G, base_g);

    k_layer_fused<0><<<256, 256, 0, stream>>>(a0, a1, convwT, conv_b, z_bf, G, base_g,
                                              p_bf, m_part, s_part, resT, Wo_bf, Wo_b,
                                              out, ctr);
    k_layer_fused<0><<<256, 256, 0, stream>>>(a1, a0, convwT, conv_b, z_bf, G, base_g,
                                              p_bf, m_part, s_part, resT, Wo_bf, Wo_b,
                                              out, ctr + 64);
    k_layer_fused<1><<<256, 256, 0, stream>>>(a0, a1, convwT, conv_b, z_bf, G, base_g,
                                              p_bf, m_part, s_part, resT, Wo_bf, Wo_b,
                                              out, ctr + 128);
}

// Round 11
// 66.273 us; speedup vs baseline: 5.4845x; 5.4845x over previous
//
#include <hip/hip_runtime.h>
#include <hip/hip_bf16.h>
#include <math.h>

#define BB 16
#define TT 64
#define HWXY 512
#define EE 256
#define VV 128

typedef __bf16 bf16x8 __attribute__((ext_vector_type(8)));
typedef unsigned short u16x8 __attribute__((ext_vector_type(8)));
typedef float f32x4 __attribute__((ext_vector_type(4)));
typedef unsigned short u16;

__device__ __forceinline__ f32x4 mfma16(bf16x8 a, bf16x8 b, f32x4 c) {
    return __builtin_amdgcn_mfma_f32_16x16x32_bf16(a, b, c, 0, 0, 0);
}

__device__ __forceinline__ unsigned short f2bf(float f) {
    union { float f; unsigned int i; } v; v.f = f;
    unsigned int x = v.i;
    return (unsigned short)((x + 0x7fffu + ((x >> 16) & 1u)) >> 16);  // RNE
}

__device__ __forceinline__ float bf2f(unsigned short u) {
    union { unsigned int i; float f; } v; v.i = ((unsigned int)u) << 16;
    return v.f;
}

__device__ __forceinline__ u16x8 pack8(float4 v0, float4 v1) {
    u16x8 o;
    o[0] = f2bf(v0.x); o[1] = f2bf(v0.y); o[2] = f2bf(v0.z); o[3] = f2bf(v0.w);
    o[4] = f2bf(v1.x); o[5] = f2bf(v1.y); o[6] = f2bf(v1.z); o[7] = f2bf(v1.w);
    return o;
}

// Async global->LDS DMA, 16B/lane. LDS dest wave-uniform; lane i lands at
// dest + i*16. Per-lane global src carries any gather/swizzle.
__device__ __forceinline__ void dma16(const void* g, void* l) {
    __builtin_amdgcn_global_load_lds(
        (const __attribute__((address_space(1))) void*)g,
        (__attribute__((address_space(3))) void*)l, 16, 0, 0);
}

#define VMWAIT0() do { asm volatile("s_waitcnt vmcnt(0)" ::: "memory"); \
                       __builtin_amdgcn_sched_barrier(0); } while (0)

// ---------------------------------------------------------------------------
// Setup: LDS-tiled transposes (resT, convwT, W^T) + vectorized elementwise
// ---------------------------------------------------------------------------
__global__ __launch_bounds__(256) void k_setup(
    const float* __restrict__ enc, const float* __restrict__ dec,
    const int* __restrict__ labels, const float* __restrict__ embed,
    const float* __restrict__ conv_w, const float* __restrict__ W_w,
    const float* __restrict__ Wo_w,
    u16* __restrict__ s_bf, u16* __restrict__ dec_bf, u16* __restrict__ resT,
    u16* __restrict__ convwT, u16* __restrict__ WT, u16* __restrict__ Wo_bf) {
    __shared__ unsigned short tl[64][66];
    int bid = blockIdx.x;
    if (bid < 512) {
        const int b = bid >> 5, rem = bid & 31;
        const int s0 = (rem >> 2) << 6, e0 = (rem & 3) << 6;
#pragma unroll
        for (int it = 0; it < 16; ++it) {
            int lin = threadIdx.x + it * 256;
            int sl = lin >> 6, el = lin & 63;
            int src = (b * HWXY + s0 + sl) * EE + e0 + el;
            float dv = dec[src];
            dec_bf[src] = f2bf(dv);
            tl[sl][el] = f2bf(enc[src] + dv);
        }
        __syncthreads();
#pragma unroll
        for (int it = 0; it < 16; ++it) {
            int lin = threadIdx.x + it * 256;
            int el = lin >> 6, sl = lin & 63;
            resT[(b * EE + e0 + el) * HWXY + s0 + sl] = tl[sl][el];
        }
        return;
    }
    bid -= 512;
    if (bid < 96) {
        const int c0 = (bid >> 3) << 6, j0 = (bid & 7) << 6;
#pragma unroll
        for (int it = 0; it < 16; ++it) {
            int lin = threadIdx.x + it * 256;
            int cl = lin >> 6, jl = lin & 63;
            tl[cl][jl] = f2bf(conv_w[(c0 + cl) * 512 + j0 + jl]);
        }
        __syncthreads();
#pragma unroll
        for (int it = 0; it < 16; ++it) {
            int lin = threadIdx.x + it * 256;
            int jl = lin >> 6, cl = lin & 63;
            convwT[(j0 + jl) * 768 + c0 + cl] = tl[cl][jl];
        }
        return;
    }
    bid -= 96;
    if (bid < 16) {
        // WT[e][e'] = W_w[e'][e]
        const int c0 = (bid >> 2) << 6, j0 = (bid & 3) << 6;
#pragma unroll
        for (int it = 0; it < 16; ++it) {
            int lin = threadIdx.x + it * 256;
            int cl = lin >> 6, jl = lin & 63;
            tl[cl][jl] = f2bf(W_w[(c0 + cl) * 256 + j0 + jl]);
        }
        __syncthreads();
#pragma unroll
        for (int it = 0; it < 16; ++it) {
            int lin = threadIdx.x + it * 256;
            int el = lin >> 6, pl = lin & 63;
            WT[(j0 + el) * 256 + c0 + pl] = tl[pl][el];
        }
        return;
    }
    bid -= 16;
    int i8 = (bid * 256 + threadIdx.x) * 8;
    const int n1 = BB * TT * EE;
    if (i8 < n1) {
        int b = i8 >> 14, t = (i8 >> 8) & 63, e = i8 & 255;
        int lab = labels[b * TT + t];
        const float* ep = embed + lab * EE + e;
        float4 v0 = *(const float4*)ep, v1 = *(const float4*)(ep + 4);
        *(u16x8*)(s_bf + i8) = pack8(v0, v1);
        return;
    }
    i8 -= n1;
    float4 v0 = *(const float4*)(Wo_w + i8), v1 = *(const float4*)(Wo_w + i8 + 4);
    *(u16x8*)(Wo_bf + i8) = pack8(v0, v1);
}

// ---------------------------------------------------------------------------
// k_precomp (runs once): grid 640.
//  [0,256):   G[b,s,e] = sum_e' dec[b,s,e'] WT[e][e']
//  [256,384): base[b,t,s] = sum_e' (s[t,e']+W_b[e']) dec[b,s,e']
//  [384,640): conv layer-1 (a_in = s_bf) -> z_bf
// ---------------------------------------------------------------------------
__global__ __launch_bounds__(256) void k_precomp(
    const u16* __restrict__ dec_bf, const u16* __restrict__ WT,
    const u16* __restrict__ s_bf, const float* __restrict__ W_b,
    u16* __restrict__ G, float* __restrict__ base_g,
    const u16* __restrict__ convwT, const float* __restrict__ conv_b,
    u16* __restrict__ z_bf) {
    __shared__ __align__(16) char smem[98304];
    char* const As = smem;
    char* const Bs = smem + 32768;
    const int tid = threadIdx.x;
    const int w = tid >> 6, L = tid & 63, l16 = L & 15, lg = L >> 4;
    int bid = blockIdx.x;

    if (bid < 256) {
        const int b = bid >> 4, st = (bid >> 1) & 7, et = bid & 1;
#pragma unroll
        for (int i = 0; i < 8; ++i) {
            const int p = w * 8 + i;
            const int r = 2 * p + (L >> 5);
            dma16(dec_bf + (b * HWXY + st * 64 + r) * EE + (((L & 31) ^ (r & 7)) << 3),
                  As + p * 1024);
        }
#pragma unroll
        for (int i = 0; i < 16; ++i) {
            const int slot = w * 16 + i;
            const int kc = slot >> 3, nf = slot & 7;
            dma16(WT + (et * 128 + nf * 16 + l16) * EE + kc * 32 + lg * 8,
                  Bs + slot * 1024);
        }
        VMWAIT0();
        __syncthreads();
        f32x4 acc[4][2] = {{{0,0,0,0},{0,0,0,0}},{{0,0,0,0},{0,0,0,0}},
                           {{0,0,0,0},{0,0,0,0}},{{0,0,0,0},{0,0,0,0}}};
#pragma unroll
        for (int kc = 0; kc < 8; ++kc) {
#pragma unroll
            for (int m = 0; m < 4; ++m) {
                const int arow = m * 16 + l16;
                const bf16x8 af = *(const bf16x8*)(
                    As + arow * 512 + (((kc * 4 + lg) ^ (arow & 7)) << 4));
                acc[m][0] = mfma16(af, *(const bf16x8*)(Bs + (kc * 8 + w * 2) * 1024 + L * 16), acc[m][0]);
                acc[m][1] = mfma16(af, *(const bf16x8*)(Bs + (kc * 8 + w * 2 + 1) * 1024 + L * 16), acc[m][1]);
            }
        }
#pragma unroll
        for (int m = 0; m < 4; ++m)
#pragma unroll
            for (int nf = 0; nf < 2; ++nf)
#pragma unroll
                for (int j = 0; j < 4; ++j) {
                    const int s = st * 64 + m * 16 + lg * 4 + j;
                    const int e = et * 128 + w * 32 + nf * 16 + l16;
                    G[(b * HWXY + s) * EE + e] = f2bf(acc[m][nf][j]);
                }
        return;
    }
    if (bid < 384) {
        bid -= 256;
        const int b = bid >> 3, st = bid & 7;
#pragma unroll
        for (int it = 0; it < 8; ++it) {
            int unit = tid + it * 256;
            int row = unit >> 5, ch = unit & 31;
            u16x8 v = *(const u16x8*)(s_bf + (b * TT + row) * EE + ch * 8);
            u16x8 o;
#pragma unroll
            for (int k = 0; k < 8; ++k) o[k] = f2bf(bf2f(v[k]) + W_b[ch * 8 + k]);
            *(u16x8*)(As + row * 512 + ((ch ^ (row & 7)) << 4)) = o;
        }
#pragma unroll
        for (int i = 0; i < 8; ++i) {
            const int slot = w * 8 + i;
            const int kc = slot >> 2, nf = slot & 3;
            dma16(dec_bf + (b * HWXY + st * 64 + nf * 16 + l16) * EE + kc * 32 + lg * 8,
                  Bs + slot * 1024);
        }
        VMWAIT0();
        __syncthreads();
        f32x4 acc[4] = {{0,0,0,0},{0,0,0,0},{0,0,0,0},{0,0,0,0}};
        const int arow = w * 16 + l16;
#pragma unroll
        for (int kc = 0; kc < 8; ++kc) {
            const bf16x8 af = *(const bf16x8*)(
                As + arow * 512 + (((kc * 4 + lg) ^ (arow & 7)) << 4));
#pragma unroll
            for (int nf = 0; nf < 4; ++nf)
                acc[nf] = mfma16(af, *(const bf16x8*)(Bs + (kc * 4 + nf) * 1024 + L * 16), acc[nf]);
        }
#pragma unroll
        for (int nf = 0; nf < 4; ++nf)
#pragma unroll
            for (int j = 0; j < 4; ++j) {
                const int t = w * 16 + lg * 4 + j;
                base_g[(b * TT + t) * HWXY + st * 64 + nf * 16 + l16] = acc[nf][j];
            }
        return;
    }
    // ---- conv layer 1 (a_in = s_bf) ----
    {
        bid -= 384;
        const int ct = bid >> 4, b = bid & 15;
        char* const Ac = smem;              // 66 x 512 swizzled
        char* const Bc = smem + 33792;      // 48 slots x 1KB
#pragma unroll
        for (int i = 0; i < 12; ++i) {
            const int slot = w * 12 + i;
            const int kc = slot >> 1, half = slot & 1;
            dma16(convwT + (ct * 16 + l16 + half * 256) * 768 + kc * 32 + lg * 8,
                  Bc + slot * 1024);
        }
#pragma unroll
        for (int i = 0; i < 8; ++i) {
            const int p = w * 8 + i;
            const int r = 1 + 2 * p + (L >> 5);
            dma16(s_bf + (b * TT + r - 1) * EE + (((L & 31) ^ (r & 7)) << 3),
                  Ac + 512 + p * 1024);
        }
        if (tid < 64) {
            char* dst = (tid < 32) ? (Ac + tid * 16) : (Ac + 65 * 512 + (tid - 32) * 16);
            *(u16x8*)dst = (u16x8){0,0,0,0,0,0,0,0};
        }
        VMWAIT0();
        __syncthreads();

        f32x4 za = {0,0,0,0}, zb = {0,0,0,0};
#pragma unroll
        for (int kt = 0; kt < 3; ++kt) {
            const int arow = w * 16 + l16 + kt;
            const char* ab = Ac + arow * 512;
            const int swz = (arow & 7) << 4;
#pragma unroll
            for (int ec = 0; ec < 8; ++ec) {
                const bf16x8 af = *(const bf16x8*)(ab + ((ec * 64 + lg * 16) ^ swz));
                const int kc = kt * 8 + ec;
                za = mfma16(af, *(const bf16x8*)(Bc + (kc * 2) * 1024 + L * 16), za);
                zb = mfma16(af, *(const bf16x8*)(Bc + (kc * 2 + 1) * 1024 + L * 16), zb);
            }
        }
        const int p = ct * 16 + l16;
        const float cbA = conv_b[p], cbB = conv_b[p + 256];
#pragma unroll
        for (int j = 0; j < 4; ++j) {
            const int t = w * 16 + lg * 4 + j;
            const float v = za[j] + cbA, u = zb[j] + cbB;
            z_bf[(b * TT + t) * EE + p] = f2bf(v / (1.0f + __expf(-u)));
        }
    }
}

// ---------------------------------------------------------------------------
// K1: conv(K=3,E->2E)+GLU -> z. grid (b=16, ct=16), block 256. All-DMA.
// b in blockIdx.x => id%8 == b%8: all blocks of a batch on one XCD (L2-local).
// ---------------------------------------------------------------------------
__global__ __launch_bounds__(256) void k_conv(
    const u16* __restrict__ a_in, const u16* __restrict__ convwT,
    const float* __restrict__ conv_b, u16* __restrict__ z_bf) {
    __shared__ __align__(16) char As[33792];
    __shared__ __align__(16) char Bs[49152];
    const int b = blockIdx.x, ct = blockIdx.y;
    const int tid = threadIdx.x;
    const int w = tid >> 6, L = tid & 63, l16 = L & 15, lg = L >> 4;

#pragma unroll
    for (int i = 0; i < 12; ++i) {
        const int slot = w * 12 + i;
        const int kc = slot >> 1, half = slot & 1;
        dma16(convwT + (ct * 16 + l16 + half * 256) * 768 + kc * 32 + lg * 8,
              Bs + slot * 1024);
    }
#pragma unroll
    for (int i = 0; i < 8; ++i) {
        const int p = w * 8 + i;
        const int r = 1 + 2 * p + (L >> 5);
        dma16(a_in + (b * TT + r - 1) * EE + (((L & 31) ^ (r & 7)) << 3),
              As + 512 + p * 1024);
    }
    if (tid < 64) {
        char* dst = (tid < 32) ? (As + tid * 16) : (As + 65 * 512 + (tid - 32) * 16);
        *(u16x8*)dst = (u16x8){0,0,0,0,0,0,0,0};
    }
    VMWAIT0();
    __syncthreads();

    f32x4 za = {0,0,0,0}, zb = {0,0,0,0};
#pragma unroll
    for (int kt = 0; kt < 3; ++kt) {
        const int arow = w * 16 + l16 + kt;
        const char* ab = As + arow * 512;
        const int swz = (arow & 7) << 4;
#pragma unroll
        for (int ec = 0; ec < 8; ++ec) {
            const bf16x8 af = *(const bf16x8*)(ab + ((ec * 64 + lg * 16) ^ swz));
            const int kc = kt * 8 + ec;
            za = mfma16(af, *(const bf16x8*)(Bs + (kc * 2) * 1024 + L * 16), za);
            zb = mfma16(af, *(const bf16x8*)(Bs + (kc * 2 + 1) * 1024 + L * 16), zb);
        }
    }
    const int p = ct * 16 + l16;
    const float cbA = conv_b[p], cbB = conv_b[p + 256];
#pragma unroll
    for (int j = 0; j < 4; ++j) {
        const int t = w * 16 + lg * 4 + j;
        const float v = za[j] + cbA, u = zb[j] + cbB;
        z_bf[(b * TT + t) * EE + p] = f2bf(v / (1.0f + __expf(-u)));
    }
}

// ---------------------------------------------------------------------------
// K3: scores = z@G^T + base, partial softmax per 32-col block.
// grid (b=16, st=16), block 256. Writes p_un bf16 + m/s partials.
// ---------------------------------------------------------------------------
__global__ __launch_bounds__(256) void k_scores(
    const u16* __restrict__ z_bf, const u16* __restrict__ G,
    const float* __restrict__ base_g, u16* __restrict__ p_bf,
    float* __restrict__ m_part, float* __restrict__ s_part) {
    __shared__ __align__(16) char Zs[32768];
    __shared__ __align__(16) char Gs[16384];
    __shared__ float basel[64 * 36];
    const int b = blockIdx.x, st = blockIdx.y;
    const int tid = threadIdx.x;
    const int w = tid >> 6, L = tid & 63, l16 = L & 15, lg = L >> 4;

#pragma unroll
    for (int i = 0; i < 8; ++i) {
        const int p = w * 8 + i;
        const int r = 2 * p + (L >> 5);
        dma16(z_bf + (b * TT + r) * EE + (((L & 31) ^ (r & 7)) << 3), Zs + p * 1024);
    }
#pragma unroll
    for (int i = 0; i < 4; ++i) {
        const int slot = w * 4 + i;
        const int kc = slot >> 1, nf = slot & 1;
        dma16(G + (b * HWXY + st * 32 + nf * 16 + l16) * EE + kc * 32 + lg * 8,
              Gs + slot * 1024);
    }
    {
        const int row = tid >> 2, c0 = (tid & 3) * 8;
        const float* src = base_g + (b * TT + row) * HWXY + st * 32 + c0;
        float4 v0 = *(const float4*)src, v1 = *(const float4*)(src + 4);
        *(float4*)(basel + row * 36 + c0) = v0;
        *(float4*)(basel + row * 36 + c0 + 4) = v1;
    }
    VMWAIT0();
    __syncthreads();

    f32x4 sc[2] = {{0,0,0,0},{0,0,0,0}};
    const int arow = w * 16 + l16;
#pragma unroll
    for (int kc = 0; kc < 8; ++kc) {
        const bf16x8 af = *(const bf16x8*)(
            Zs + arow * 512 + (((kc * 4 + lg) ^ (arow & 7)) << 4));
        sc[0] = mfma16(af, *(const bf16x8*)(Gs + (kc * 2) * 1024 + L * 16), sc[0]);
        sc[1] = mfma16(af, *(const bf16x8*)(Gs + (kc * 2 + 1) * 1024 + L * 16), sc[1]);
    }
    float pm[4], ps[4];
#pragma unroll
    for (int j = 0; j < 4; ++j) {
        const int row = w * 16 + lg * 4 + j;
        sc[0][j] += basel[row * 36 + l16];
        sc[1][j] += basel[row * 36 + 16 + l16];
        float m = fmaxf(sc[0][j], sc[1][j]);
#pragma unroll
        for (int off = 8; off >= 1; off >>= 1) m = fmaxf(m, __shfl_xor(m, off));
        pm[j] = m;
        const float p0 = __expf(sc[0][j] - m);
        const float p1 = __expf(sc[1][j] - m);
        sc[0][j] = p0; sc[1][j] = p1;
        float s = p0 + p1;
#pragma unroll
        for (int off = 8; off >= 1; off >>= 1) s += __shfl_xor(s, off);
        ps[j] = s;
    }
    if (l16 == 0) {
#pragma unroll
        for (int j = 0; j < 4; ++j) {
            const int t = w * 16 + lg * 4 + j;
            m_part[(b * 16 + st) * TT + t] = pm[j];
            s_part[(b * 16 + st) * TT + t] = ps[j];
        }
    }
#pragma unroll
    for (int nf = 0; nf < 2; ++nf)
#pragma unroll
        for (int j = 0; j < 4; ++j) {
            const int t = w * 16 + lg * 4 + j;
            p_bf[(b * TT + t) * HWXY + st * 32 + nf * 16 + l16] = f2bf(sc[nf][j]);
        }
}

// ---------------------------------------------------------------------------
// K5: a = softmax-normalized(p_un) . res^T + z. grid (b=16, et=8, tt=2).
// ---------------------------------------------------------------------------
__global__ __launch_bounds__(256) void k_attn(
    const u16* __restrict__ p_bf, const u16* __restrict__ resT,
    const u16* __restrict__ z_bf, const float* __restrict__ m_part,
    const float* __restrict__ s_part, u16* __restrict__ a_out) {
    __shared__ __align__(16) char Ps[32768];
    __shared__ __align__(16) char Bs[32768];
    __shared__ u16 Zr[1024];
    __shared__ float mp[512], sp[512];
    const int b = blockIdx.x, et = blockIdx.y, tt = blockIdx.z;
    const int tid = threadIdx.x;
    const int w = tid >> 6, L = tid & 63, l16 = L & 15, lg = L >> 4;

#pragma unroll
    for (int i = 0; i < 8; ++i) {
        const int r = w * 8 + i;
        dma16(p_bf + (b * TT + tt * 32 + r) * HWXY + ((L ^ (r & 7)) << 3), Ps + r * 1024);
    }
#pragma unroll
    for (int i = 0; i < 8; ++i) {
        const int slot = w * 8 + i;
        const int kc = slot >> 1, nf = slot & 1;
        dma16(resT + (b * EE + et * 32 + nf * 16 + l16) * HWXY + kc * 32 + lg * 8,
              Bs + slot * 1024);
    }
    {
        if (tid < 128) {
            const int t = tid >> 2, part = tid & 3;
            *(u16x8*)(Zr + t * 32 + part * 8) =
                *(const u16x8*)(z_bf + (b * TT + tt * 32 + t) * EE + et * 32 + part * 8);
        }
        const int stl = tid >> 5, tl = tid & 31;
        mp[tid] = m_part[(b * 16 + stl) * TT + tt * 32 + tl];
        sp[tid] = s_part[(b * 16 + stl) * TT + tt * 32 + tl];
        mp[tid + 256] = m_part[(b * 16 + stl + 8) * TT + tt * 32 + tl];
        sp[tid + 256] = s_part[(b * 16 + stl + 8) * TT + tt * 32 + tl];
    }
    VMWAIT0();
    __syncthreads();

    const int mg = w >> 1, nh = w & 1;
    float corr[4][16];
#pragma unroll
    for (int j = 0; j < 4; ++j) {
        const int row = mg * 16 + lg * 4 + j;
        float mgl = mp[row];
#pragma unroll
        for (int s = 1; s < 16; ++s) mgl = fmaxf(mgl, mp[s * 32 + row]);
        float S = 0.f;
#pragma unroll
        for (int s = 0; s < 16; ++s) {
            const float c = __expf(mp[s * 32 + row] - mgl);
            corr[j][s] = c;
            S += sp[s * 32 + row] * c;
        }
        const float is = 1.0f / S;
#pragma unroll
        for (int s = 0; s < 16; ++s) corr[j][s] *= is;
    }

    f32x4 ca = {0,0,0,0};
    const int arow = mg * 16 + l16;
#pragma unroll
    for (int st = 0; st < 16; ++st) {
        const bf16x8 af = *(const bf16x8*)(
            Ps + arow * 1024 + (((st * 4 + lg) ^ (arow & 7)) << 4));
        f32x4 t0 = mfma16(af, *(const bf16x8*)(Bs + (st * 2 + nh) * 1024 + L * 16),
                          (f32x4){0,0,0,0});
#pragma unroll
        for (int j = 0; j < 4; ++j) ca[j] += t0[j] * corr[j][st];
    }
#pragma unroll
    for (int j = 0; j < 4; ++j) {
        const int row = mg * 16 + lg * 4 + j;
        const int t = tt * 32 + row;
        a_out[(b * TT + t) * EE + et * 32 + nh * 16 + l16] =
            f2bf(ca[j] + bf2f(Zr[row * 32 + nh * 16 + l16]));
    }
}

// ---------------------------------------------------------------------------
// K6: logits + log_softmax. grid (b=16, tt=4), block 256. All-DMA staging.
// ---------------------------------------------------------------------------
__global__ __launch_bounds__(256) void k_logits(
    const u16* __restrict__ a_bf, const u16* __restrict__ Wo_bf,
    const float* __restrict__ Wo_b, float* __restrict__ out) {
    __shared__ __align__(16) char As[8192];
    __shared__ __align__(16) char Ws[65536];
    __shared__ float red_m[64], red_s[64];
    const int b = blockIdx.x, tt = blockIdx.y;
    const int tid = threadIdx.x;
    const int w = tid >> 6, L = tid & 63, l16 = L & 15, lg = L >> 4;

#pragma unroll
    for (int i = 0; i < 2; ++i) {
        const int p = w * 2 + i;
        const int row = p * 2 + (L >> 5);
        dma16(a_bf + (b * TT + tt * 16 + row) * EE + (((L & 31) ^ (row & 7)) << 3),
              As + p * 1024);
    }
#pragma unroll
    for (int i = 0; i < 16; ++i) {
        const int slot = w * 16 + i;
        const int kc = slot >> 3, vg = slot & 7;
        dma16(Wo_bf + (vg * 16 + l16) * EE + kc * 32 + lg * 8, Ws + slot * 1024);
    }
    VMWAIT0();
    __syncthreads();

    f32x4 l0 = {0,0,0,0}, l1 = {0,0,0,0};
#pragma unroll
    for (int kc = 0; kc < 8; ++kc) {
        const bf16x8 af = *(const bf16x8*)(As + l16 * 512 + ((kc * 64 + lg * 16) ^ ((l16 & 7) << 4)));
        l0 = mfma16(af, *(const bf16x8*)(Ws + (kc * 8 + w * 2) * 1024 + L * 16), l0);
        l1 = mfma16(af, *(const bf16x8*)(Ws + (kc * 8 + w * 2 + 1) * 1024 + L * 16), l1);
    }
    const int v0 = w * 32 + l16, v1 = v0 + 16;
    const float wb0 = Wo_b[v0], wb1 = Wo_b[v1];
    float lv0[4], lv1[4], mg[4];
#pragma unroll
    for (int j = 0; j < 4; ++j) {
        lv0[j] = l0[j] + wb0;
        lv1[j] = l1[j] + wb1;
        float m = fmaxf(lv0[j], lv1[j]);
#pragma unroll
        for (int off = 8; off >= 1; off >>= 1) m = fmaxf(m, __shfl_xor(m, off));
        if (l16 == 0) red_m[(lg * 4 + j) * 4 + w] = m;
    }
    __syncthreads();
#pragma unroll
    for (int j = 0; j < 4; ++j) {
        const int row = lg * 4 + j;
        float m = red_m[row * 4 + 0];
#pragma unroll
        for (int ww = 1; ww < 4; ++ww) m = fmaxf(m, red_m[row * 4 + ww]);
        mg[j] = m;
        float s = __expf(lv0[j] - m) + __expf(lv1[j] - m);
#pragma unroll
        for (int off = 8; off >= 1; off >>= 1) s += __shfl_xor(s, off);
        if (l16 == 0) red_s[row * 4 + w] = s;
    }
    __syncthreads();
#pragma unroll
    for (int j = 0; j < 4; ++j) {
        const int row = lg * 4 + j;
        float s = red_s[row * 4 + 0] + red_s[row * 4 + 1] + red_s[row * 4 + 2] + red_s[row * 4 + 3];
        const float lse = mg[j] + __logf(s);
        const int gt = b * TT + tt * 16 + row;
        out[gt * VV + v0] = lv0[j] - lse;
        out[gt * VV + v1] = lv1[j] - lse;
    }
}

// ---------------------------------------------------------------------------
extern "C" void kernel_launch(void* const* d_in, const int* in_sizes, int n_in,
                              void* d_out, int out_size, void* d_ws, size_t ws_size,
                              hipStream_t stream) {
    const float* enc    = (const float*)d_in[0];
    const float* dec    = (const float*)d_in[1];
    const int*   labels = (const int*)d_in[2];
    const float* embed  = (const float*)d_in[3];
    const float* conv_w = (const float*)d_in[4];
    const float* conv_b = (const float*)d_in[5];
    const float* W_w    = (const float*)d_in[6];
    const float* W_b    = (const float*)d_in[7];
    const float* Wo_w   = (const float*)d_in[8];
    const float* Wo_b   = (const float*)d_in[9];
    float* out = (float*)d_out;
    char* ws = (char*)d_ws;

    u16*   a0     = (u16*)(ws + 0x000000);
    u16*   a1     = (u16*)(ws + 0x080000);
    u16*   s_bf   = (u16*)(ws + 0x100000);
    u16*   dec_bf = (u16*)(ws + 0x180000);
    u16*   resT   = (u16*)(ws + 0x580000);
    u16*   convwT = (u16*)(ws + 0x980000);
    u16*   WT     = (u16*)(ws + 0xA40000);
    u16*   Wo_bf  = (u16*)(ws + 0xA60000);
    u16*   z_bf   = (u16*)(ws + 0xA80000);
    u16*   p_bf   = (u16*)(ws + 0xB00000);
    float* m_part = (float*)(ws + 0xC00000);
    float* s_part = (float*)(ws + 0xC10000);
    float* base_g = (float*)(ws + 0xC20000);
    u16*   G      = (u16*)(ws + 0xE20000);

    k_setup<<<768, 256, 0, stream>>>(enc, dec, labels, embed, conv_w, W_w, Wo_w,
                                     s_bf, dec_bf, resT, convwT, WT, Wo_bf);
    k_precomp<<<640, 256, 0, stream>>>(dec_bf, WT, s_bf, W_b, G, base_g,
                                       convwT, conv_b, z_bf);

    // Layer 1 (conv already done in k_precomp): scores -> attn -> a1
    k_scores<<<dim3(16, 16), 256, 0, stream>>>(z_bf, G, base_g, p_bf, m_part, s_part);
    k_attn<<<dim3(16, 8, 2), 256, 0, stream>>>(p_bf, resT, z_bf, m_part, s_part, a1);

    // Layer 2: a1 -> a0
    k_conv<<<dim3(16, 16), 256, 0, stream>>>(a1, convwT, conv_b, z_bf);
    k_scores<<<dim3(16, 16), 256, 0, stream>>>(z_bf, G, base_g, p_bf, m_part, s_part);
    k_attn<<<dim3(16, 8, 2), 256, 0, stream>>>(p_bf, resT, z_bf, m_part, s_part, a0);

    // Layer 3: a0 -> a1
    k_conv<<<dim3(16, 16), 256, 0, stream>>>(a0, convwT, conv_b, z_bf);
    k_scores<<<dim3(16, 16), 256, 0, stream>>>(z_bf, G, base_g, p_bf, m_part, s_part);
    k_attn<<<dim3(16, 8, 2), 256, 0, stream>>>(p_bf, resT, z_bf, m_part, s_part, a1);

    k_logits<<<dim3(16, 4), 256, 0, stream>>>(a1, Wo_bf, Wo_b, out);
}